// Round 12
// baseline (94.633 us; speedup 1.0000x reference)
//
#include <hip/hip_runtime.h>

// KiloNeRF fused MLP — 32x32x16 MFMA, layer-folded version.
// Per 32-point tile: C = W^T(32xK) @ act(Kx32) via mfma_f32_32x32x16_f16.
// Positional k-map sigma(hi,j) = (j&3)+8*(j>>2)+4*hi on BOTH A and B keeps
// activations lane-local (C row r -> slot j=r for lo, j=r-8 (+16) for hi).
// R12: FOLD the feature layer into the view layer:
//   h2 = relu(feat @ Wv_feat + views @ Wv_views + bv)
//      = relu(h1 @ (wf·Wv_feat) + [bv + bf·Wv_feat] + viewpart)
//   Wc = wf·Wv_feat and bvEff computed in f32 at setup (one-time), so the
//   chain loses 2 MFMAs + 1 pack boundary. viewpart accumulator cv is the
//   C-init of the folded layer. Plus cross-iteration x prefetch.
// sigma on the f32 VALU pipe (16 FMA + shfl_xor(32)); br/bs at store.

#define NPTS   4194304
#define NT32   (NPTS / 32)

typedef _Float16 f16;
typedef _Float16 f16x2 __attribute__((ext_vector_type(2)));
typedef _Float16 f16x8 __attribute__((ext_vector_type(8)));
typedef float    f32x16 __attribute__((ext_vector_type(16)));

union H8 { f16x8 v; unsigned u[4]; };

static __device__ __forceinline__ unsigned pkrtz(float a, float b) {
    return __builtin_bit_cast(unsigned, __builtin_amdgcn_cvt_pkrtz(a, b));
}
static __device__ __forceinline__ unsigned relu2(unsigned w) {
    f16x2 h = __builtin_bit_cast(f16x2, w);
    f16x2 z = (f16x2)(f16)0.f;
    return __builtin_bit_cast(unsigned, __builtin_elementwise_max(h, z));
}

#define MFMA32(A, B, C) __builtin_amdgcn_mfma_f32_32x32x16_f16((A), (B), (C), 0, 0, 0)

__global__ __launch_bounds__(256, 4) void kilonerf_r12(
    const float* __restrict__ x,
    const float* __restrict__ w0, const float* __restrict__ b0,
    const float* __restrict__ w1, const float* __restrict__ b1,
    const float* __restrict__ wf, const float* __restrict__ bf,
    const float* __restrict__ ws, const float* __restrict__ bs,
    const float* __restrict__ wv, const float* __restrict__ bv,
    const float* __restrict__ wr, const float* __restrict__ br,
    float* __restrict__ out)
{
    const int lane = threadIdx.x & 63;
    const int m  = lane & 31;     // output channel (A row) / point (B,C col)
    const int hi = lane >> 5;     // lane half

    int sj[8], row[16];
#pragma unroll
    for (int j = 0; j < 8; ++j)  sj[j]  = (j & 3) + 8 * (j >> 2) + 4 * hi;
#pragma unroll
    for (int r = 0; r < 16; ++r) row[r] = (r & 3) + 8 * (r >> 2) + 4 * hi;

    // ---- effective view-layer bias: bv + bf·Wv_feat ----
    float bve = bv[m];
#pragma unroll 8
    for (int k = 0; k < 32; ++k) bve = fmaf(wv[k * 32 + m], bf[k], bve);

    // ---- one-time weight fragment gathers ----
    // aw0x: w0 rows k=0..2, b0 at k=3. awv2x: wv view rows at k=4..6, bve at k=7.
    // awc = (wf · Wv_feat) composed in f32, then RTN to f16.
    f16x8 aw0x, awv2x, aw1lo, aw1hi, awclo, awchi, awrlo, awrhi;
#pragma unroll
    for (int j = 0; j < 8; ++j) {
        const int k = sj[j];
        aw0x[j]  = (k < 3) ? (f16)w0[k * 32 + m]
                  : (k == 3 ? (f16)b0[m] : (f16)0.f);
        awv2x[j] = (k >= 4 && k < 7) ? (f16)wv[(32 + (k - 4)) * 32 + m]
                  : (k == 7 ? (f16)bve : (f16)0.f);
        aw1lo[j] = (f16)w1[k * 32 + m];
        aw1hi[j] = (f16)w1[(16 + k) * 32 + m];
        float wc0 = 0.f, wc1 = 0.f;
#pragma unroll 8
        for (int t = 0; t < 32; ++t) {
            wc0 = fmaf(wf[k * 32 + t],        wv[t * 32 + m], wc0);
            wc1 = fmaf(wf[(16 + k) * 32 + t], wv[t * 32 + m], wc1);
        }
        awclo[j] = (f16)wc0;
        awchi[j] = (f16)wc1;
        awrlo[j] = (m < 3) ? (f16)wr[k * 3 + m] : (f16)0.f;
        awrhi[j] = (m < 3) ? (f16)wr[(16 + k) * 3 + m] : (f16)0.f;
    }

    // sigma weights (f32) and L1 bias C-init
    float wsv[16];
    f32x16 b1c;
#pragma unroll
    for (int r = 0; r < 16; ++r) {
        wsv[r] = ws[row[r]];
        b1c[r] = b1[row[r]];
    }

    const float br0 = br[0], br1 = br[1], br2 = br[2], bs0 = bs[0];

    f32x16 zf;
#pragma unroll
    for (int r = 0; r < 16; ++r) zf[r] = 0.f;

    const int wslot  = blockIdx.x * 4 + (threadIdx.x >> 6);
    const int nslots = gridDim.x * 4;   // 8192 waves

    // ---- prefetch first tile's x ----
    float2 cx0, cx1, cx2;
    {
        const float2* xp2 = reinterpret_cast<const float2*>(
            x + (size_t)(wslot * 32 + m) * 6);
        cx0 = xp2[0]; cx1 = xp2[1]; cx2 = xp2[2];
    }

    for (int tile = wslot; tile < NT32; tile += nslots) {
        // issue next tile's loads early (wraps to a valid address at end)
        int np = tile + nslots; if (np >= NT32) np = wslot;
        const float2* xn = reinterpret_cast<const float2*>(
            x + (size_t)(np * 32 + m) * 6);
        float2 nx0 = xn[0], nx1 = xn[1], nx2 = xn[2];

        // merged input fragment: hi=0 -> {p0,p1,p2,1} at k=0..3,
        //                        hi=1 -> {v0,v1,v2,1} at k=4..7
        const float fa = hi ? cx1.y : cx0.x;
        const float fb = hi ? cx2.x : cx0.y;
        const float fc = hi ? cx2.y : cx1.x;
        H8 bx;
        bx.u[0] = pkrtz(fa, fb);
        bx.u[1] = pkrtz(fc, 1.0f);
        bx.u[2] = 0u;
        bx.u[3] = 0u;

        // ---- layer 0 (+b0) and view-partial (+bvEff): independent ----
        f32x16 c0 = MFMA32(aw0x, bx.v, zf);
        f32x16 cv = MFMA32(awv2x, bx.v, zf);

        H8 blo, bhi;
        blo.u[0] = relu2(pkrtz(c0[0], c0[1]));
        blo.u[1] = relu2(pkrtz(c0[2], c0[3]));
        blo.u[2] = relu2(pkrtz(c0[4], c0[5]));
        blo.u[3] = relu2(pkrtz(c0[6], c0[7]));
        bhi.u[0] = relu2(pkrtz(c0[8], c0[9]));
        bhi.u[1] = relu2(pkrtz(c0[10], c0[11]));
        bhi.u[2] = relu2(pkrtz(c0[12], c0[13]));
        bhi.u[3] = relu2(pkrtz(c0[14], c0[15]));

        // ---- layer 1: 32 -> 32 (+b1 via C-init), relu ----
        f32x16 c1 = MFMA32(aw1lo, blo.v, b1c);
        c1 = MFMA32(aw1hi, bhi.v, c1);

        // sigma on the VALU pipe: ws . relu(h1)
        float s0 = 0.f, s1 = 0.f, s2 = 0.f, s3 = 0.f;
#pragma unroll
        for (int r = 0; r < 4; ++r) {
            s0 = fmaf(fmaxf(c1[r],      0.f), wsv[r],      s0);
            s1 = fmaf(fmaxf(c1[4 + r],  0.f), wsv[4 + r],  s1);
            s2 = fmaf(fmaxf(c1[8 + r],  0.f), wsv[8 + r],  s2);
            s3 = fmaf(fmaxf(c1[12 + r], 0.f), wsv[12 + r], s3);
        }
        float sg = (s0 + s1) + (s2 + s3);
        sg += __shfl_xor(sg, 32);

        blo.u[0] = relu2(pkrtz(c1[0], c1[1]));
        blo.u[1] = relu2(pkrtz(c1[2], c1[3]));
        blo.u[2] = relu2(pkrtz(c1[4], c1[5]));
        blo.u[3] = relu2(pkrtz(c1[6], c1[7]));
        bhi.u[0] = relu2(pkrtz(c1[8], c1[9]));
        bhi.u[1] = relu2(pkrtz(c1[10], c1[11]));
        bhi.u[2] = relu2(pkrtz(c1[12], c1[13]));
        bhi.u[3] = relu2(pkrtz(c1[14], c1[15]));

        // ---- folded feature+view layer: h1·Wc + cv, relu ----
        f32x16 cc = MFMA32(awclo, blo.v, cv);
        cc = MFMA32(awchi, bhi.v, cc);

        blo.u[0] = relu2(pkrtz(cc[0], cc[1]));
        blo.u[1] = relu2(pkrtz(cc[2], cc[3]));
        blo.u[2] = relu2(pkrtz(cc[4], cc[5]));
        blo.u[3] = relu2(pkrtz(cc[6], cc[7]));
        bhi.u[0] = relu2(pkrtz(cc[8], cc[9]));
        bhi.u[1] = relu2(pkrtz(cc[10], cc[11]));
        bhi.u[2] = relu2(pkrtz(cc[12], cc[13]));
        bhi.u[3] = relu2(pkrtz(cc[14], cc[15]));

        // ---- rgb: 32 -> 3 (rows 0..2 valid; +br at store) ----
        f32x16 cr = MFMA32(awrlo, blo.v, zf);
        cr = MFMA32(awrhi, bhi.v, cr);

        // ---- store: hi==0 lanes hold rgb rows 0..2 for their point ----
        if (hi == 0) {
            float4 o = make_float4(cr[0] + br0, cr[1] + br1,
                                   cr[2] + br2, sg + bs0);
            *reinterpret_cast<float4*>(out + (size_t)(tile * 32 + m) * 4) = o;
        }

        cx0 = nx0; cx1 = nx1; cx2 = nx2;
    }
}

extern "C" void kernel_launch(void* const* d_in, const int* in_sizes, int n_in,
                              void* d_out, int out_size, void* d_ws, size_t ws_size,
                              hipStream_t stream) {
    const float* x  = (const float*)d_in[0];
    const float* w0 = (const float*)d_in[1];
    const float* b0 = (const float*)d_in[2];
    const float* w1 = (const float*)d_in[3];
    const float* b1 = (const float*)d_in[4];
    const float* wf = (const float*)d_in[5];
    const float* bf = (const float*)d_in[6];
    const float* ws = (const float*)d_in[7];
    const float* bs = (const float*)d_in[8];
    const float* wv = (const float*)d_in[9];
    const float* bv = (const float*)d_in[10];
    const float* wr = (const float*)d_in[11];
    const float* br = (const float*)d_in[12];
    float* out = (float*)d_out;

    dim3 block(256);
    dim3 grid(2048);
    kilonerf_r12<<<grid, block, 0, stream>>>(x, w0, b0, w1, b1, wf, bf,
                                             ws, bs, wv, bv, wr, br, out);
}

// Round 14
// 57.883 us; speedup vs baseline: 1.6349x; 1.6349x over previous
//
#include <hip/hip_runtime.h>

// KiloNeRF fused MLP — 32x32x16 MFMA, layer-folded, prep-kernel version.
// R14 = R13 + the missing sigma-bias at store (bs0), which was R13's sole
// failure (absmax 4e-2 == |bs[0]|).
//   prep:  Wc[k][m] = sum_t wf[k][t]*wv[t][m]   (f32, 1024 threads)
//          bvEff[m] = bv[m] + sum_t bf[t]*wv[t][m]
//   main:  per 32-pt tile: 8 MFMAs -
//          L0(+b0) | viewpart(+bvEff) -> L1(+b1) -> folded(h1·Wc + cv) -> rgb
// sigma on the f32 VALU pipe; br/bs at store; cross-iteration x prefetch.

#define NPTS   4194304
#define NT32   (NPTS / 32)

typedef _Float16 f16;
typedef _Float16 f16x2 __attribute__((ext_vector_type(2)));
typedef _Float16 f16x8 __attribute__((ext_vector_type(8)));
typedef float    f32x16 __attribute__((ext_vector_type(16)));

union H8 { f16x8 v; unsigned u[4]; };

static __device__ __forceinline__ unsigned pkrtz(float a, float b) {
    return __builtin_bit_cast(unsigned, __builtin_amdgcn_cvt_pkrtz(a, b));
}
static __device__ __forceinline__ unsigned relu2(unsigned w) {
    f16x2 h = __builtin_bit_cast(f16x2, w);
    f16x2 z = (f16x2)(f16)0.f;
    return __builtin_bit_cast(unsigned, __builtin_elementwise_max(h, z));
}

#define MFMA32(A, B, C) __builtin_amdgcn_mfma_f32_32x32x16_f16((A), (B), (C), 0, 0, 0)

// ---- prep: compose Wc (1024 f32) and bvEff (32 f32) into workspace ----
__global__ __launch_bounds__(1024) void kilonerf_prep(
    const float* __restrict__ wf, const float* __restrict__ bf,
    const float* __restrict__ wv, const float* __restrict__ bv,
    float* __restrict__ ws_out)
{
    const int tid = threadIdx.x;
    const int k = tid >> 5, m = tid & 31;
    float acc = 0.f;
#pragma unroll 8
    for (int t = 0; t < 32; ++t)
        acc = fmaf(wf[k * 32 + t], wv[t * 32 + m], acc);
    ws_out[k * 32 + m] = acc;          // Wc
    if (tid < 32) {
        float b = bv[tid];
#pragma unroll 8
        for (int t = 0; t < 32; ++t)
            b = fmaf(bf[t], wv[t * 32 + tid], b);
        ws_out[1024 + tid] = b;        // bvEff
    }
}

__global__ __launch_bounds__(256, 4) void kilonerf_r14(
    const float* __restrict__ x,
    const float* __restrict__ w0, const float* __restrict__ b0,
    const float* __restrict__ w1, const float* __restrict__ b1,
    const float* __restrict__ ws, const float* __restrict__ bs,
    const float* __restrict__ wv, const float* __restrict__ wr,
    const float* __restrict__ br,
    const float* __restrict__ wsp,   // workspace: Wc[1024], bvEff[32]
    float* __restrict__ out)
{
    const int lane = threadIdx.x & 63;
    const int m  = lane & 31;     // output channel (A row) / point (B,C col)
    const int hi = lane >> 5;     // lane half

    int sj[8], row[16];
#pragma unroll
    for (int j = 0; j < 8; ++j)  sj[j]  = (j & 3) + 8 * (j >> 2) + 4 * hi;
#pragma unroll
    for (int r = 0; r < 16; ++r) row[r] = (r & 3) + 8 * (r >> 2) + 4 * hi;

    const float* Wc    = wsp;
    const float* bvEff = wsp + 1024;

    // ---- one-time weight fragment gathers (all cached loads) ----
    f16x8 aw0x, awv2x, aw1lo, aw1hi, awclo, awchi, awrlo, awrhi;
#pragma unroll
    for (int j = 0; j < 8; ++j) {
        const int k = sj[j];
        aw0x[j]  = (k < 3) ? (f16)w0[k * 32 + m]
                  : (k == 3 ? (f16)b0[m] : (f16)0.f);
        awv2x[j] = (k >= 4 && k < 7) ? (f16)wv[(32 + (k - 4)) * 32 + m]
                  : (k == 7 ? (f16)bvEff[m] : (f16)0.f);
        aw1lo[j] = (f16)w1[k * 32 + m];
        aw1hi[j] = (f16)w1[(16 + k) * 32 + m];
        awclo[j] = (f16)Wc[k * 32 + m];
        awchi[j] = (f16)Wc[(16 + k) * 32 + m];
        awrlo[j] = (m < 3) ? (f16)wr[k * 3 + m] : (f16)0.f;
        awrhi[j] = (m < 3) ? (f16)wr[(16 + k) * 3 + m] : (f16)0.f;
    }

    // sigma weights (f32) and L1 bias C-init
    float wsv[16];
    f32x16 b1c;
#pragma unroll
    for (int r = 0; r < 16; ++r) {
        wsv[r] = ws[row[r]];
        b1c[r] = b1[row[r]];
    }

    const float br0 = br[0], br1 = br[1], br2 = br[2], bs0 = bs[0];

    f32x16 zf;
#pragma unroll
    for (int r = 0; r < 16; ++r) zf[r] = 0.f;

    const int wslot  = blockIdx.x * 4 + (threadIdx.x >> 6);
    const int nslots = gridDim.x * 4;   // 8192 waves

    // ---- prefetch first tile's x ----
    float2 cx0, cx1, cx2;
    {
        const float2* xp2 = reinterpret_cast<const float2*>(
            x + (size_t)(wslot * 32 + m) * 6);
        cx0 = xp2[0]; cx1 = xp2[1]; cx2 = xp2[2];
    }

    for (int tile = wslot; tile < NT32; tile += nslots) {
        // issue next tile's loads early (wraps to a valid address at end)
        int np = tile + nslots; if (np >= NT32) np = wslot;
        const float2* xn = reinterpret_cast<const float2*>(
            x + (size_t)(np * 32 + m) * 6);
        float2 nx0 = xn[0], nx1 = xn[1], nx2 = xn[2];

        // merged input fragment: hi=0 -> {p0,p1,p2,1} at k=0..3,
        //                        hi=1 -> {v0,v1,v2,1} at k=4..7
        const float fa = hi ? cx1.y : cx0.x;
        const float fb = hi ? cx2.x : cx0.y;
        const float fc = hi ? cx2.y : cx1.x;
        H8 bx;
        bx.u[0] = pkrtz(fa, fb);
        bx.u[1] = pkrtz(fc, 1.0f);
        bx.u[2] = 0u;
        bx.u[3] = 0u;

        // ---- layer 0 (+b0) and view-partial (+bvEff): independent ----
        f32x16 c0 = MFMA32(aw0x, bx.v, zf);
        f32x16 cv = MFMA32(awv2x, bx.v, zf);

        H8 blo, bhi;
        blo.u[0] = relu2(pkrtz(c0[0], c0[1]));
        blo.u[1] = relu2(pkrtz(c0[2], c0[3]));
        blo.u[2] = relu2(pkrtz(c0[4], c0[5]));
        blo.u[3] = relu2(pkrtz(c0[6], c0[7]));
        bhi.u[0] = relu2(pkrtz(c0[8], c0[9]));
        bhi.u[1] = relu2(pkrtz(c0[10], c0[11]));
        bhi.u[2] = relu2(pkrtz(c0[12], c0[13]));
        bhi.u[3] = relu2(pkrtz(c0[14], c0[15]));

        // ---- layer 1: 32 -> 32 (+b1 via C-init), relu ----
        f32x16 c1 = MFMA32(aw1lo, blo.v, b1c);
        c1 = MFMA32(aw1hi, bhi.v, c1);

        // sigma on the VALU pipe: ws . relu(h1)
        float s0 = 0.f, s1 = 0.f, s2 = 0.f, s3 = 0.f;
#pragma unroll
        for (int r = 0; r < 4; ++r) {
            s0 = fmaf(fmaxf(c1[r],      0.f), wsv[r],      s0);
            s1 = fmaf(fmaxf(c1[4 + r],  0.f), wsv[4 + r],  s1);
            s2 = fmaf(fmaxf(c1[8 + r],  0.f), wsv[8 + r],  s2);
            s3 = fmaf(fmaxf(c1[12 + r], 0.f), wsv[12 + r], s3);
        }
        float sg = (s0 + s1) + (s2 + s3);
        sg += __shfl_xor(sg, 32);

        blo.u[0] = relu2(pkrtz(c1[0], c1[1]));
        blo.u[1] = relu2(pkrtz(c1[2], c1[3]));
        blo.u[2] = relu2(pkrtz(c1[4], c1[5]));
        blo.u[3] = relu2(pkrtz(c1[6], c1[7]));
        bhi.u[0] = relu2(pkrtz(c1[8], c1[9]));
        bhi.u[1] = relu2(pkrtz(c1[10], c1[11]));
        bhi.u[2] = relu2(pkrtz(c1[12], c1[13]));
        bhi.u[3] = relu2(pkrtz(c1[14], c1[15]));

        // ---- folded feature+view layer: h1·Wc + cv, relu ----
        f32x16 cc = MFMA32(awclo, blo.v, cv);
        cc = MFMA32(awchi, bhi.v, cc);

        blo.u[0] = relu2(pkrtz(cc[0], cc[1]));
        blo.u[1] = relu2(pkrtz(cc[2], cc[3]));
        blo.u[2] = relu2(pkrtz(cc[4], cc[5]));
        blo.u[3] = relu2(pkrtz(cc[6], cc[7]));
        bhi.u[0] = relu2(pkrtz(cc[8], cc[9]));
        bhi.u[1] = relu2(pkrtz(cc[10], cc[11]));
        bhi.u[2] = relu2(pkrtz(cc[12], cc[13]));
        bhi.u[3] = relu2(pkrtz(cc[14], cc[15]));

        // ---- rgb: 32 -> 3 (rows 0..2 valid; +br at store) ----
        f32x16 cr = MFMA32(awrlo, blo.v, zf);
        cr = MFMA32(awrhi, bhi.v, cr);

        // ---- store: hi==0 lanes hold rgb rows 0..2 for their point ----
        if (hi == 0) {
            float4 o = make_float4(cr[0] + br0, cr[1] + br1,
                                   cr[2] + br2, sg + bs0);
            *reinterpret_cast<float4*>(out + (size_t)(tile * 32 + m) * 4) = o;
        }

        cx0 = nx0; cx1 = nx1; cx2 = nx2;
    }
}

extern "C" void kernel_launch(void* const* d_in, const int* in_sizes, int n_in,
                              void* d_out, int out_size, void* d_ws, size_t ws_size,
                              hipStream_t stream) {
    const float* x  = (const float*)d_in[0];
    const float* w0 = (const float*)d_in[1];
    const float* b0 = (const float*)d_in[2];
    const float* w1 = (const float*)d_in[3];
    const float* b1 = (const float*)d_in[4];
    const float* wf = (const float*)d_in[5];
    const float* bf = (const float*)d_in[6];
    const float* ws = (const float*)d_in[7];
    const float* bs = (const float*)d_in[8];
    const float* wv = (const float*)d_in[9];
    const float* bv = (const float*)d_in[10];
    const float* wr = (const float*)d_in[11];
    const float* br = (const float*)d_in[12];
    float* out = (float*)d_out;
    float* wsp = (float*)d_ws;

    kilonerf_prep<<<dim3(1), dim3(1024), 0, stream>>>(wf, bf, wv, bv, wsp);

    dim3 block(256);
    dim3 grid(2048);
    kilonerf_r14<<<grid, block, 0, stream>>>(x, w0, b0, w1, b1,
                                             ws, bs, wv, wr, br, wsp, out);
}

// Round 15
// 57.467 us; speedup vs baseline: 1.6467x; 1.0072x over previous
//
#include <hip/hip_runtime.h>

// KiloNeRF fused MLP — 32x32x16 MFMA, layer-folded, AGPR-diet version.
// R15 = R14 with accumulator-liveness cuts (occupancy was AGPR-limited:
// 60 VGPR + ~112 AGPR = 172 regs -> 11.9 waves/CU = measured 35%):
//  - view-partial cv computed LATE (right before folded layer) from the
//    still-live bx, instead of spanning the whole chain.
//  - folded layer accumulates in-place into cv.
//  - sigma via __builtin_amdgcn_fdot2 on packed relu(h1) f16 words:
//    8 dot2 (f32 accum) replace 16 fmax + 16 fma; ws kept packed (8 regs).
//   prep:  Wc[k][m] = sum_t wf[k][t]*wv[t][m];  bvEff = bv + bf·Wv_feat
//   main:  L0(+b0) -> L1(+b1) -> [cv: views+bvEff] -> folded(h1·Wc+cv) -> rgb
// br/bs at store; cross-iteration x prefetch.

#define NPTS   4194304
#define NT32   (NPTS / 32)

typedef _Float16 f16;
typedef _Float16 f16x2 __attribute__((ext_vector_type(2)));
typedef _Float16 f16x8 __attribute__((ext_vector_type(8)));
typedef __fp16   h16x2 __attribute__((ext_vector_type(2)));
typedef float    f32x16 __attribute__((ext_vector_type(16)));

union H8 { f16x8 v; unsigned u[4]; };

static __device__ __forceinline__ unsigned pkrtz(float a, float b) {
    return __builtin_bit_cast(unsigned, __builtin_amdgcn_cvt_pkrtz(a, b));
}
static __device__ __forceinline__ unsigned relu2(unsigned w) {
    f16x2 h = __builtin_bit_cast(f16x2, w);
    f16x2 z = (f16x2)(f16)0.f;
    return __builtin_bit_cast(unsigned, __builtin_elementwise_max(h, z));
}
static __device__ __forceinline__ float fdot2(unsigned a, unsigned b, float c) {
    return __builtin_amdgcn_fdot2(__builtin_bit_cast(h16x2, a),
                                  __builtin_bit_cast(h16x2, b), c, false);
}

#define MFMA32(A, B, C) __builtin_amdgcn_mfma_f32_32x32x16_f16((A), (B), (C), 0, 0, 0)

// ---- prep: compose Wc (1024 f32) and bvEff (32 f32) into workspace ----
__global__ __launch_bounds__(1024) void kilonerf_prep(
    const float* __restrict__ wf, const float* __restrict__ bf,
    const float* __restrict__ wv, const float* __restrict__ bv,
    float* __restrict__ ws_out)
{
    const int tid = threadIdx.x;
    const int k = tid >> 5, m = tid & 31;
    float acc = 0.f;
#pragma unroll 8
    for (int t = 0; t < 32; ++t)
        acc = fmaf(wf[k * 32 + t], wv[t * 32 + m], acc);
    ws_out[k * 32 + m] = acc;          // Wc
    if (tid < 32) {
        float b = bv[tid];
#pragma unroll 8
        for (int t = 0; t < 32; ++t)
            b = fmaf(bf[t], wv[t * 32 + tid], b);
        ws_out[1024 + tid] = b;        // bvEff
    }
}

__global__ __launch_bounds__(256, 4) void kilonerf_r15(
    const float* __restrict__ x,
    const float* __restrict__ w0, const float* __restrict__ b0,
    const float* __restrict__ w1, const float* __restrict__ b1,
    const float* __restrict__ ws, const float* __restrict__ bs,
    const float* __restrict__ wv, const float* __restrict__ wr,
    const float* __restrict__ br,
    const float* __restrict__ wsp,   // workspace: Wc[1024], bvEff[32]
    float* __restrict__ out)
{
    const int lane = threadIdx.x & 63;
    const int m  = lane & 31;     // output channel (A row) / point (B,C col)
    const int hi = lane >> 5;     // lane half

    int sj[8], row[16];
#pragma unroll
    for (int j = 0; j < 8; ++j)  sj[j]  = (j & 3) + 8 * (j >> 2) + 4 * hi;
#pragma unroll
    for (int r = 0; r < 16; ++r) row[r] = (r & 3) + 8 * (r >> 2) + 4 * hi;

    const float* Wc    = wsp;
    const float* bvEff = wsp + 1024;

    // ---- one-time weight fragment gathers (all cached loads) ----
    f16x8 aw0x, awv2x, aw1lo, aw1hi, awclo, awchi, awrlo, awrhi;
#pragma unroll
    for (int j = 0; j < 8; ++j) {
        const int k = sj[j];
        aw0x[j]  = (k < 3) ? (f16)w0[k * 32 + m]
                  : (k == 3 ? (f16)b0[m] : (f16)0.f);
        awv2x[j] = (k >= 4 && k < 7) ? (f16)wv[(32 + (k - 4)) * 32 + m]
                  : (k == 7 ? (f16)bvEff[m] : (f16)0.f);
        aw1lo[j] = (f16)w1[k * 32 + m];
        aw1hi[j] = (f16)w1[(16 + k) * 32 + m];
        awclo[j] = (f16)Wc[k * 32 + m];
        awchi[j] = (f16)Wc[(16 + k) * 32 + m];
        awrlo[j] = (m < 3) ? (f16)wr[k * 3 + m] : (f16)0.f;
        awrhi[j] = (m < 3) ? (f16)wr[(16 + k) * 3 + m] : (f16)0.f;
    }

    // sigma weights packed f16: word w pairs channels (row[2w], row[2w+1])
    unsigned wspk[8];
#pragma unroll
    for (int w = 0; w < 8; ++w)
        wspk[w] = pkrtz(ws[row[2 * w]], ws[row[2 * w + 1]]);

    // L1 bias C-init
    f32x16 b1c;
#pragma unroll
    for (int r = 0; r < 16; ++r) b1c[r] = b1[row[r]];

    const float br0 = br[0], br1 = br[1], br2 = br[2], bs0 = bs[0];

    f32x16 zf;
#pragma unroll
    for (int r = 0; r < 16; ++r) zf[r] = 0.f;

    const int wslot  = blockIdx.x * 4 + (threadIdx.x >> 6);
    const int nslots = gridDim.x * 4;   // 8192 waves

    // ---- prefetch first tile's x ----
    float2 cx0, cx1, cx2;
    {
        const float2* xp2 = reinterpret_cast<const float2*>(
            x + (size_t)(wslot * 32 + m) * 6);
        cx0 = xp2[0]; cx1 = xp2[1]; cx2 = xp2[2];
    }

    for (int tile = wslot; tile < NT32; tile += nslots) {
        // issue next tile's loads early (wraps to a valid address at end)
        int np = tile + nslots; if (np >= NT32) np = wslot;
        const float2* xn = reinterpret_cast<const float2*>(
            x + (size_t)(np * 32 + m) * 6);
        float2 nx0 = xn[0], nx1 = xn[1], nx2 = xn[2];

        // merged input fragment: hi=0 -> {p0,p1,p2,1} at k=0..3,
        //                        hi=1 -> {v0,v1,v2,1} at k=4..7
        const float fa = hi ? cx1.y : cx0.x;
        const float fb = hi ? cx2.x : cx0.y;
        const float fc = hi ? cx2.y : cx1.x;
        H8 bx;
        bx.u[0] = pkrtz(fa, fb);
        bx.u[1] = pkrtz(fc, 1.0f);
        bx.u[2] = 0u;
        bx.u[3] = 0u;

        // ---- layer 0: 3 -> 32 (+b0 via k=3), relu ----
        f32x16 c0 = MFMA32(aw0x, bx.v, zf);

        H8 blo, bhi;
        blo.u[0] = relu2(pkrtz(c0[0], c0[1]));
        blo.u[1] = relu2(pkrtz(c0[2], c0[3]));
        blo.u[2] = relu2(pkrtz(c0[4], c0[5]));
        blo.u[3] = relu2(pkrtz(c0[6], c0[7]));
        bhi.u[0] = relu2(pkrtz(c0[8], c0[9]));
        bhi.u[1] = relu2(pkrtz(c0[10], c0[11]));
        bhi.u[2] = relu2(pkrtz(c0[12], c0[13]));
        bhi.u[3] = relu2(pkrtz(c0[14], c0[15]));

        // ---- layer 1: 32 -> 32 (+b1 via C-init), relu ----
        f32x16 c1 = MFMA32(aw1lo, blo.v, b1c);
        c1 = MFMA32(aw1hi, bhi.v, c1);

        blo.u[0] = relu2(pkrtz(c1[0], c1[1]));
        blo.u[1] = relu2(pkrtz(c1[2], c1[3]));
        blo.u[2] = relu2(pkrtz(c1[4], c1[5]));
        blo.u[3] = relu2(pkrtz(c1[6], c1[7]));
        bhi.u[0] = relu2(pkrtz(c1[8], c1[9]));
        bhi.u[1] = relu2(pkrtz(c1[10], c1[11]));
        bhi.u[2] = relu2(pkrtz(c1[12], c1[13]));
        bhi.u[3] = relu2(pkrtz(c1[14], c1[15]));

        // sigma = ws . relu(h1) via packed dot2 (f32 accumulate)
        float s0 = 0.f, s1 = 0.f;
#pragma unroll
        for (int w = 0; w < 4; ++w) {
            s0 = fdot2(blo.u[w], wspk[w], s0);
            s1 = fdot2(bhi.u[w], wspk[4 + w], s1);
        }
        float sg = s0 + s1;
        sg += __shfl_xor(sg, 32);

        // ---- view partial (late): views(3)+bvEff from still-live bx ----
        f32x16 cv = MFMA32(awv2x, bx.v, zf);

        // ---- folded feature+view layer: h1·Wc + cv (in-place), relu ----
        cv = MFMA32(awclo, blo.v, cv);
        cv = MFMA32(awchi, bhi.v, cv);

        blo.u[0] = relu2(pkrtz(cv[0], cv[1]));
        blo.u[1] = relu2(pkrtz(cv[2], cv[3]));
        blo.u[2] = relu2(pkrtz(cv[4], cv[5]));
        blo.u[3] = relu2(pkrtz(cv[6], cv[7]));
        bhi.u[0] = relu2(pkrtz(cv[8], cv[9]));
        bhi.u[1] = relu2(pkrtz(cv[10], cv[11]));
        bhi.u[2] = relu2(pkrtz(cv[12], cv[13]));
        bhi.u[3] = relu2(pkrtz(cv[14], cv[15]));

        // ---- rgb: 32 -> 3 (rows 0..2 valid; +br at store) ----
        f32x16 cr = MFMA32(awrlo, blo.v, zf);
        cr = MFMA32(awrhi, bhi.v, cr);

        // ---- store: hi==0 lanes hold rgb rows 0..2 for their point ----
        if (hi == 0) {
            float4 o = make_float4(cr[0] + br0, cr[1] + br1,
                                   cr[2] + br2, sg + bs0);
            *reinterpret_cast<float4*>(out + (size_t)(tile * 32 + m) * 4) = o;
        }

        cx0 = nx0; cx1 = nx1; cx2 = nx2;
    }
}

extern "C" void kernel_launch(void* const* d_in, const int* in_sizes, int n_in,
                              void* d_out, int out_size, void* d_ws, size_t ws_size,
                              hipStream_t stream) {
    const float* x  = (const float*)d_in[0];
    const float* w0 = (const float*)d_in[1];
    const float* b0 = (const float*)d_in[2];
    const float* w1 = (const float*)d_in[3];
    const float* b1 = (const float*)d_in[4];
    const float* wf = (const float*)d_in[5];
    const float* bf = (const float*)d_in[6];
    const float* ws = (const float*)d_in[7];
    const float* bs = (const float*)d_in[8];
    const float* wv = (const float*)d_in[9];
    const float* bv = (const float*)d_in[10];
    const float* wr = (const float*)d_in[11];
    const float* br = (const float*)d_in[12];
    float* out = (float*)d_out;
    float* wsp = (float*)d_ws;

    kilonerf_prep<<<dim3(1), dim3(1024), 0, stream>>>(wf, bf, wv, bv, wsp);

    dim3 block(256);
    dim3 grid(2048);
    kilonerf_r15<<<grid, block, 0, stream>>>(x, w0, b0, w1, b1,
                                             ws, bs, wv, wr, br, wsp, out);
}